// Round 15
// baseline (222.139 us; speedup 1.0000x reference)
//
#include <hip/hip_runtime.h>
#include <stdint.h>

#define T_ROWS 1500000
#define N_ROWS 2000000
#define N_SEL  1048576
#define G_CNT  (N_SEL/4)
#define LB     (N_ROWS - N_SEL)
#define TILE   8192                            // 245 blocks -> exactly 1 block/CU
#define NBLK   ((N_ROWS + TILE - 1)/TILE)     // 245
#define NBLK1  (NBLK + 1)                      // 246 (row stride; last col = total)
#define STHREADS 1024                          // scatter block (16 waves)
#define SWAVES 16
#define WTILE  (TILE/SWAVES)                   // 512
#define WROUNDS (WTILE/64)                     // 8
#define HTHREADS 512
#define BINS   256
#define NB_MX  ((T_ROWS + HTHREADS - 1)/HTHREADS)   // 2930

static_assert((uint64_t)NBLK * TILE >= N_ROWS, "tile coverage");
static_assert(TILE % (SWAVES * 64) == 0, "wave partition");
static_assert(NBLK <= 256, "one block per CU (balance)");
static_assert(T_ROWS < (1 << 21), "tp fits 21 bits");
static_assert((LB * 4) % 16 == 0, "finalize uint4 alignment");
static_assert(NBLK + 256 <= 1024, "hist+scan co-residency (spin safety)");

// Counters: cnts[p*64] for pass p (256B apart). Zeroed every call by zero_cnts.
__global__ void zero_cnts(uint32_t* __restrict__ cnts) {
    cnts[threadIdx.x * 64] = 0u;   // 64 threads cover 4 used counters + slack
}

// Scan block body: wait for NBLK producer blocks (relaxed spin + one acquire),
// then wave 0 exclusive-scans digit-row `digit` in place; total -> row[NBLK].
__device__ __forceinline__ void scan_block(uint32_t* __restrict__ gH,
                                           uint32_t* __restrict__ cnt, int digit) {
    const int t = threadIdx.x;
    if (t == 0) {
        while (__hip_atomic_load(cnt, __ATOMIC_RELAXED, __HIP_MEMORY_SCOPE_AGENT) < NBLK)
            __builtin_amdgcn_s_sleep(1);
        (void)__hip_atomic_load(cnt, __ATOMIC_ACQUIRE, __HIP_MEMORY_SCOPE_AGENT);
    }
    __syncthreads();          // publish acquire to whole block
    if (t < 64) {
        const int lane = t;
        uint32_t* row = gH + (size_t)digit * NBLK1;
        uint32_t carry = 0;
        for (int b0 = 0; b0 < NBLK; b0 += 64) {
            int i = b0 + lane;
            uint32_t v = (i < NBLK) ? row[i] : 0u;
            uint32_t s = v;
            #pragma unroll
            for (int off = 1; off < 64; off <<= 1) {
                uint32_t tt = __shfl_up(s, off, 64);
                if (lane >= off) s += tt;
            }
            if (i < NBLK) row[i] = s - v + carry;
            carry += __shfl(s, 63, 64);
        }
        if (lane == 0) row[NBLK] = carry;
    }
}

// code = (descending-orderable key << 32) | (flag!=0 << 21) | tp.
// LSD radix over bits [32,64) is stable -> ties keep original (index-ascending)
// order == jnp.argsort(-bt). Payload carries everything finalize needs.
// build fuses codes + mxtab + pass-0 per-tile histogram + pass-0 rowscan
// (256 trailing scan blocks, release/acquire handoff within the kernel).
__global__ __launch_bounds__(HTHREADS) void build_all(
        const float* __restrict__ nb, const float* __restrict__ td,
        uint64_t* __restrict__ codes, float* __restrict__ mxtab,
        uint32_t* __restrict__ gH, uint32_t* __restrict__ cnts) {
    const int b = blockIdx.x;
    if (b >= NBLK + NB_MX) {                       // scan blocks (last in grid)
        scan_block(gH, &cnts[0], b - (NBLK + NB_MX));
        return;
    }
    if (b >= NBLK) {                               // mxtab blocks
        int i = (b - NBLK) * HTHREADS + threadIdx.x;
        if (i < T_ROWS) {
            float4 r = *(const float4*)(td + (size_t)i * 4);
            mxtab[i] = fmaxf(r.y, fmaxf(r.z, r.w));
        }
        return;
    }
    __shared__ uint32_t h[BINS];
    const int t = threadIdx.x;
    if (t < BINS) h[t] = 0;
    __syncthreads();
    const int base = b * TILE;
    #pragma unroll
    for (int r = 0; r < TILE / HTHREADS; ++r) {
        int i = base + r * HTHREADS + t;
        if (i < N_ROWS) {
            const float* row = nb + (size_t)i * 5;
            uint32_t u = __float_as_uint(row[1]);
            uint32_t ku = (u & 0x80000000u) ? ~u : (u | 0x80000000u); // asc uint == asc float
            uint32_t kd = ~ku;                                        // asc uint == desc float
            uint32_t tp = (uint32_t)(int)row[0];                      // exact: integral f32
            uint32_t fl = (row[4] != 0.0f) ? 1u : 0u;
            codes[i] = ((uint64_t)kd << 32) | (fl << 21) | tp;
            atomicAdd(&h[kd & (BINS - 1)], 1u);   // uniform byte: plain atomics cheap
        }
    }
    __syncthreads();
    if (t < BINS) gH[(size_t)t * NBLK1 + b] = h[t];
    __syncthreads();                               // all gH stores drained (vmcnt)
    if (t == 0)
        __hip_atomic_fetch_add(&cnts[0], 1u, __ATOMIC_RELEASE, __HIP_MEMORY_SCOPE_AGENT);
}

// Uniform-digit histogram + fused rowscan. uint4 loads (2 codes), plain LDS atomics.
template <int SHIFT32, int PASS>
__global__ __launch_bounds__(HTHREADS) void radix_hist_u(
        const uint64_t* __restrict__ src, uint32_t* __restrict__ gH,
        uint32_t* __restrict__ cnts) {
    const int b = blockIdx.x;
    if (b >= NBLK) { scan_block(gH, &cnts[PASS * 64], b - NBLK); return; }
    __shared__ uint32_t h[BINS];
    const int t = threadIdx.x;
    if (t < BINS) h[t] = 0;
    __syncthreads();
    const uint4* s4 = (const uint4*)(src + (size_t)b * TILE);
    const int pairBase = b * (TILE / 2);
    #pragma unroll
    for (int r = 0; r < TILE / (2 * HTHREADS); ++r) {
        int j = r * HTHREADS + t;                 // pair index within tile
        uint4 v = s4[j];                          // codes 2j, 2j+1 (alloc covers pad)
        int i0 = (pairBase + j) * 2;
        if (i0 < N_ROWS)     atomicAdd(&h[(v.y >> SHIFT32) & (BINS - 1)], 1u);
        if (i0 + 1 < N_ROWS) atomicAdd(&h[(v.w >> SHIFT32) & (BINS - 1)], 1u);
    }
    __syncthreads();
    if (t < BINS) gH[(size_t)t * NBLK1 + b] = h[t];
    __syncthreads();
    if (t == 0)
        __hip_atomic_fetch_add(&cnts[PASS * 64], 1u, __ATOMIC_RELEASE, __HIP_MEMORY_SCOPE_AGENT);
}

// Skewed-digit histogram (top byte) + fused rowscan: ballot-leader counting.
template <int SHIFT32, int PASS>
__global__ __launch_bounds__(HTHREADS) void radix_hist_s(
        const uint64_t* __restrict__ src, uint32_t* __restrict__ gH,
        uint32_t* __restrict__ cnts) {
    const int b = blockIdx.x;
    if (b >= NBLK) { scan_block(gH, &cnts[PASS * 64], b - NBLK); return; }
    __shared__ uint32_t h[BINS];
    const int t = threadIdx.x;
    const int lane = t & 63;
    if (t < BINS) h[t] = 0;
    __syncthreads();
    const int base = b * TILE;
    const uint32_t* s32 = (const uint32_t*)src;
    #pragma unroll
    for (int r = 0; r < TILE / HTHREADS; ++r) {
        int i = base + r * HTHREADS + t;
        bool active = (i < N_ROWS);
        uint32_t d = 0;
        if (active) d = (s32[2 * (size_t)i + 1] >> SHIFT32) & (BINS - 1);
        uint64_t m = __ballot(active ? 1 : 0);
        #pragma unroll
        for (int bb = 0; bb < 8; ++bb) {
            uint64_t x = __ballot((active && ((d >> bb) & 1u)) ? 1 : 0);
            m = ((d >> bb) & 1u) ? (m & x) : (m & ~x);
        }
        int ldr = __ffsll((unsigned long long)m) - 1;
        if (active && lane == ldr) atomicAdd(&h[d], (uint32_t)__popcll(m));
    }
    __syncthreads();
    if (t < BINS) gH[(size_t)t * NBLK1 + b] = h[t];
    __syncthreads();
    if (t == 0)
        __hip_atomic_fetch_add(&cnts[PASS * 64], 1u, __ATOMIC_RELEASE, __HIP_MEMORY_SCOPE_AGENT);
}

// 16-wave scatter. cnt32 layout [wave][digit] -> LDS-bank-conflict-free leader atomics.
// Reads gH plainly across the kernel boundary (coherent, coalesced).
template <int SHIFT, bool LAST>
__global__ __launch_bounds__(STHREADS) void radix_scatter(
        const uint64_t* __restrict__ src, uint64_t* __restrict__ dst,
        uint32_t* __restrict__ dst32, const uint32_t* __restrict__ gH) {
    __shared__ uint64_t tileS[TILE];              // 64 KB
    __shared__ uint32_t cnt32[SWAVES * BINS];     // 16 KB [wave][digit]
    __shared__ uint32_t writeBase[BINS];
    __shared__ uint32_t wpT[SWAVES], wpL[SWAVES];

    const int t = threadIdx.x;
    const int lane = t & 63;
    const int w = t >> 6;
    const int blk = blockIdx.x;
    const int base = blk * TILE;
    const int tileCount = (N_ROWS - base < TILE) ? (N_ROWS - base) : TILE;

    // early issue: this block's prefix data (scanned rows, plain cached loads)
    uint32_t rp = 0, lc = 0, tot = 0;
    if (t < BINS) {
        const uint32_t* row = gH + (size_t)t * NBLK1;
        rp = row[blk];
        lc = row[blk + 1] - rp;
        tot = row[NBLK];
    }

    #pragma unroll
    for (int k = t; k < SWAVES * BINS; k += STHREADS) cnt32[k] = 0u;
    __syncthreads();

    // ---- phase A: per-wave digit counts via ballot match; save (rank,ldr,cnt)/round
    uint64_t creg[WROUNDS];
    uint32_t meta[WROUNDS];
    const uint64_t below = (lane == 0) ? 0ull : (~0ull >> (64 - lane));
    #pragma unroll
    for (int r = 0; r < WROUNDS; ++r) {
        int idx = base + w * WTILE + r * 64 + lane;
        bool active = (idx < N_ROWS);
        uint64_t c = active ? src[idx] : 0ull;
        creg[r] = c;
        uint32_t d = (uint32_t)(c >> SHIFT) & (BINS - 1);
        uint64_t m = __ballot(active ? 1 : 0);
        #pragma unroll
        for (int bb = 0; bb < 8; ++bb) {
            uint64_t x = __ballot((active && ((d >> bb) & 1u)) ? 1 : 0);
            m = ((d >> bb) & 1u) ? (m & x) : (m & ~x);
        }
        int ldr = __ffsll((unsigned long long)m) - 1;
        uint32_t cnt = (uint32_t)__popcll(m);
        uint32_t rank = (uint32_t)__popcll(m & below);
        meta[r] = rank | ((uint32_t)(ldr < 0 ? 0 : ldr) << 8) | (cnt << 16);
        if (active && lane == ldr)
            atomicAdd(&cnt32[w * BINS + d], cnt);
    }
    __syncthreads();   // cnt32 complete

    // ---- phase B1: dual block-exclusive scans over digits (tot -> exT, lc -> exL)
    uint32_t sT = tot, sL = lc;
    #pragma unroll
    for (int off = 1; off < 64; off <<= 1) {
        uint32_t aT = __shfl_up(sT, off, 64);
        uint32_t aL = __shfl_up(sL, off, 64);
        if (lane >= off) { sT += aT; sL += aL; }
    }
    if (lane == 63) { wpT[w] = sT; wpL[w] = sL; }
    __syncthreads();
    uint32_t exT = sT - tot, exL = sL - lc;
    #pragma unroll
    for (int wv = 0; wv < SWAVES; ++wv) if (wv < w) { exT += wpT[wv]; exL += wpL[wv]; }

    // ---- phase B2: writeBase + per-wave cursors (thread t owns digit t)
    if (t < BINS) {
        writeBase[t] = exT + rp - exL;
        uint32_t run = exL;
        #pragma unroll
        for (int wv = 0; wv < SWAVES; ++wv) {
            uint32_t c0 = cnt32[wv * BINS + t];
            cnt32[wv * BINS + t] = run;
            run += c0;
        }
    }
    __syncthreads();

    // ---- phase C: ballot-free — leader atomicAdd on cursor, shfl, LDS scatter
    #pragma unroll
    for (int r = 0; r < WROUNDS; ++r) {
        int idx = base + w * WTILE + r * 64 + lane;
        bool active = (idx < N_ROWS);
        uint64_t c = creg[r];
        uint32_t d = (uint32_t)(c >> SHIFT) & (BINS - 1);
        uint32_t mt = meta[r];
        uint32_t rank = mt & 0xFFu;
        int ldr = (int)((mt >> 8) & 0xFFu);
        uint32_t cnt = mt >> 16;
        uint32_t before = 0;
        if (active && lane == ldr)
            before = atomicAdd(&cnt32[w * BINS + d], cnt);
        before = __shfl(before, ldr, 64);
        if (active) tileS[before + rank] = c;
    }
    __syncthreads();

    // ---- write-out: consecutive sorted positions share digit -> 256B avg segments
    #pragma unroll
    for (int r = 0; r < TILE / STHREADS; ++r) {
        int p = r * STHREADS + t;
        if (p < tileCount) {
            uint64_t c = tileS[p];
            uint32_t d = (uint32_t)(c >> SHIFT) & (BINS - 1);
            uint32_t g = writeBase[d] + p;
            if (!LAST) {
                dst[(size_t)g] = c;
            } else if (g >= LB) {        // only selected range is read; payload only
                dst32[g] = (uint32_t)c;
            }
        }
    }
}

__global__ void finalize(const uint32_t* __restrict__ pay, const float* __restrict__ td,
                         const float* __restrict__ mxtab, float* __restrict__ out) {
    int g = blockIdx.x * 256 + threadIdx.x;
    if (g >= G_CNT) return;
    uint4 p4 = *(const uint4*)(pay + LB + (size_t)g * 4);
    uint32_t cs[4] = {p4.x, p4.y, p4.z, p4.w};
    float maxmin = -100000.0f;
    int maxindex = -100;
    #pragma unroll
    for (int j = 0; j < 4; ++j) {
        int tp = (int)(cs[j] & 0x1FFFFFu);
        bool re1 = ((cs[j] >> 21) & 1u) != 0u;
        float mx = mxtab[tp];
        bool gt = (mx > maxmin);
        if (re1 == gt) { maxmin = mx; maxindex = tp; }
    }
    int mi = maxindex < 0 ? 0 : maxindex;   // clip lower bound; upper never binds
    float4 row = *(const float4*)(td + (size_t)mi * 4);
    *(float4*)(out + (size_t)g * 4) = row;
}

extern "C" void kernel_launch(void* const* d_in, const int* in_sizes, int n_in,
                              void* d_out, int out_size, void* d_ws, size_t ws_size,
                              hipStream_t stream) {
    const float* td = (const float*)d_in[0];
    const float* nb = (const float*)d_in[1];
    float* out = (float*)d_out;
    uint8_t* ws = (uint8_t*)d_ws;

    // layout: mxtab 6MB | gH 256*246*4 ~252KB | cnts 16KB | A @8MB | B @24MB
    float*    mxtab = (float*)(ws);
    uint32_t* gH    = (uint32_t*)(ws + (size_t)6 * 1024 * 1024);
    uint32_t* cnts  = (uint32_t*)(ws + (size_t)6 * 1024 * 1024 + 384 * 1024);
    uint64_t* A     = (uint64_t*)(ws + (size_t)8 * 1024 * 1024);
    uint64_t* B     = (uint64_t*)(ws + (size_t)24 * 1024 * 1024);

    zero_cnts<<<1, 64, 0, stream>>>(cnts);

    // build: codes + mxtab + pass-0 hist + fused pass-0 rowscan
    build_all<<<NBLK + NB_MX + 256, HTHREADS, 0, stream>>>(nb, td, A, mxtab, gH, cnts);
    radix_scatter<32, false><<<NBLK, STHREADS, 0, stream>>>(A, B, nullptr, gH);

    // pass 1: bits [40,48) — uniform digit, fused rowscan
    radix_hist_u<8, 1><<<NBLK + 256, HTHREADS, 0, stream>>>(B, gH, cnts);
    radix_scatter<40, false><<<NBLK, STHREADS, 0, stream>>>(B, A, nullptr, gH);

    // pass 2: bits [48,56) — uniform digit, fused rowscan
    radix_hist_u<16, 2><<<NBLK + 256, HTHREADS, 0, stream>>>(A, gH, cnts);
    radix_scatter<48, false><<<NBLK, STHREADS, 0, stream>>>(A, B, nullptr, gH);

    // pass 3: bits [56,64) — skewed digit, fused rowscan; slim payload-only writes
    radix_hist_s<24, 3><<<NBLK + 256, HTHREADS, 0, stream>>>(B, gH, cnts);
    radix_scatter<56, true><<<NBLK, STHREADS, 0, stream>>>(B, nullptr, (uint32_t*)A, gH);

    finalize<<<(G_CNT + 255) / 256, 256, 0, stream>>>((const uint32_t*)A, td, mxtab, out);
}

// Round 16
// 129.531 us; speedup vs baseline: 1.7149x; 1.7149x over previous
//
#include <hip/hip_runtime.h>
#include <stdint.h>

#define T_ROWS 1500000
#define N_ROWS 2000000
#define N_SEL  1048576
#define G_CNT  (N_SEL/4)
#define LB     (N_ROWS - N_SEL)
#define TILE   8192                            // 245 blocks -> exactly 1 block/CU, no quantization
#define NBLK   ((N_ROWS + TILE - 1)/TILE)     // 245
#define NBLK1  (NBLK + 1)                      // 246 (row stride; last col = total)
#define STHREADS 1024                          // scatter block (16 waves)
#define SWAVES 16
#define WTILE  (TILE/SWAVES)                   // 512
#define WROUNDS (WTILE/64)                     // 8
#define HTHREADS 512
#define BINS   256
#define NB_MX  ((T_ROWS + HTHREADS - 1)/HTHREADS)

static_assert((uint64_t)NBLK * TILE >= N_ROWS, "tile coverage");
static_assert(TILE % (SWAVES * 64) == 0, "wave partition");
static_assert(NBLK <= 256, "one block per CU (balance)");
static_assert(T_ROWS < (1 << 21), "tp fits 21 bits");
static_assert((LB * 4) % 16 == 0, "finalize uint4 alignment");

// code = (descending-orderable key << 32) | (flag!=0 << 21) | tp.
// LSD radix over bits [32,64) is stable -> ties keep original (index-ascending)
// order == jnp.argsort(-bt). Payload carries everything finalize needs.
// build fuses codes + mxtab + pass-0 per-tile histogram (uniform low byte).
__global__ __launch_bounds__(HTHREADS) void build_all(
        const float* __restrict__ nb, const float* __restrict__ td,
        uint64_t* __restrict__ codes, float* __restrict__ mxtab,
        uint32_t* __restrict__ gH) {
    const int b = blockIdx.x;
    if (b >= NBLK) {
        int i = (b - NBLK) * HTHREADS + threadIdx.x;
        if (i < T_ROWS) {
            float4 r = *(const float4*)(td + (size_t)i * 4);
            mxtab[i] = fmaxf(r.y, fmaxf(r.z, r.w));
        }
        return;
    }
    __shared__ uint32_t h[BINS];
    const int t = threadIdx.x;
    if (t < BINS) h[t] = 0;
    __syncthreads();
    const int base = b * TILE;
    #pragma unroll
    for (int r = 0; r < TILE / HTHREADS; ++r) {
        int i = base + r * HTHREADS + t;
        if (i < N_ROWS) {
            const float* row = nb + (size_t)i * 5;
            uint32_t u = __float_as_uint(row[1]);
            uint32_t ku = (u & 0x80000000u) ? ~u : (u | 0x80000000u); // asc uint == asc float
            uint32_t kd = ~ku;                                        // asc uint == desc float
            uint32_t tp = (uint32_t)(int)row[0];                      // exact: integral f32
            uint32_t fl = (row[4] != 0.0f) ? 1u : 0u;
            codes[i] = ((uint64_t)kd << 32) | (fl << 21) | tp;
            atomicAdd(&h[kd & (BINS - 1)], 1u);   // uniform byte: plain atomics cheap
        }
    }
    __syncthreads();
    if (t < BINS) gH[(size_t)t * NBLK1 + b] = h[t];
}

// Uniform-digit histogram (mantissa bytes): uint4 loads (2 codes), plain LDS atomics.
template <int SHIFT32>
__global__ __launch_bounds__(HTHREADS) void radix_hist_u(
        const uint64_t* __restrict__ src, uint32_t* __restrict__ gH) {
    __shared__ uint32_t h[BINS];
    const int t = threadIdx.x;
    if (t < BINS) h[t] = 0;
    __syncthreads();
    const uint4* s4 = (const uint4*)(src + (size_t)blockIdx.x * TILE);
    const int pairBase = blockIdx.x * (TILE / 2);
    #pragma unroll
    for (int r = 0; r < TILE / (2 * HTHREADS); ++r) {
        int j = r * HTHREADS + t;                 // pair index within tile
        uint4 v = s4[j];                          // codes 2j, 2j+1 (alloc covers pad)
        int i0 = (pairBase + j) * 2;
        if (i0 < N_ROWS)     atomicAdd(&h[(v.y >> SHIFT32) & (BINS - 1)], 1u);
        if (i0 + 1 < N_ROWS) atomicAdd(&h[(v.w >> SHIFT32) & (BINS - 1)], 1u);
    }
    __syncthreads();
    if (t < BINS) gH[(size_t)t * NBLK1 + blockIdx.x] = h[t];
}

// Skewed-digit histogram (top byte: sign+exponent): ballot-leader counting.
template <int SHIFT32>
__global__ __launch_bounds__(HTHREADS) void radix_hist_s(
        const uint64_t* __restrict__ src, uint32_t* __restrict__ gH) {
    __shared__ uint32_t h[BINS];
    const int t = threadIdx.x;
    const int lane = t & 63;
    if (t < BINS) h[t] = 0;
    __syncthreads();
    const int base = blockIdx.x * TILE;
    const uint32_t* s32 = (const uint32_t*)src;
    #pragma unroll
    for (int r = 0; r < TILE / HTHREADS; ++r) {
        int i = base + r * HTHREADS + t;
        bool active = (i < N_ROWS);
        uint32_t d = 0;
        if (active) d = (s32[2 * (size_t)i + 1] >> SHIFT32) & (BINS - 1);
        uint64_t m = __ballot(active ? 1 : 0);
        #pragma unroll
        for (int bb = 0; bb < 8; ++bb) {
            uint64_t x = __ballot((active && ((d >> bb) & 1u)) ? 1 : 0);
            m = ((d >> bb) & 1u) ? (m & x) : (m & ~x);
        }
        int ldr = __ffsll((unsigned long long)m) - 1;
        if (active && lane == ldr) atomicAdd(&h[d], (uint32_t)__popcll(m));
    }
    __syncthreads();
    if (t < BINS) gH[(size_t)t * NBLK1 + blockIdx.x] = h[t];
}

// one block per digit: exclusive scan of contiguous row; total -> row[NBLK]
__global__ void radix_rowscan(uint32_t* __restrict__ gH) {
    const int d = blockIdx.x;
    const int lane = threadIdx.x;
    uint32_t* row = gH + (size_t)d * NBLK1;
    uint32_t carry = 0;
    for (int b0 = 0; b0 < NBLK; b0 += 64) {
        int i = b0 + lane;
        uint32_t v = (i < NBLK) ? row[i] : 0u;
        uint32_t s = v;
        #pragma unroll
        for (int off = 1; off < 64; off <<= 1) {
            uint32_t tt = __shfl_up(s, off, 64);
            if (lane >= off) s += tt;
        }
        if (i < NBLK) row[i] = s - v + carry;
        carry += __shfl(s, 63, 64);
    }
    if (lane == 0) row[NBLK] = carry;
}

// 16-wave scatter. cnt32 layout [wave][digit] -> LDS-bank-conflict-free leader atomics.
template <int SHIFT, bool LAST>
__global__ __launch_bounds__(STHREADS) void radix_scatter(
        const uint64_t* __restrict__ src, uint64_t* __restrict__ dst,
        uint32_t* __restrict__ dst32, const uint32_t* __restrict__ gH) {
    __shared__ uint64_t tileS[TILE];              // 64 KB
    __shared__ uint32_t cnt32[SWAVES * BINS];     // 16 KB [wave][digit]
    __shared__ uint32_t writeBase[BINS];
    __shared__ uint32_t wpT[SWAVES], wpL[SWAVES];

    const int t = threadIdx.x;
    const int lane = t & 63;
    const int w = t >> 6;
    const int blk = blockIdx.x;
    const int base = blk * TILE;
    const int tileCount = (N_ROWS - base < TILE) ? (N_ROWS - base) : TILE;

    // early issue: this block's prefix data (scanned rows, plain cached loads)
    uint32_t rp = 0, lc = 0, tot = 0;
    if (t < BINS) {
        const uint32_t* row = gH + (size_t)t * NBLK1;
        rp = row[blk];
        lc = row[blk + 1] - rp;
        tot = row[NBLK];
    }

    #pragma unroll
    for (int k = t; k < SWAVES * BINS; k += STHREADS) cnt32[k] = 0u;
    __syncthreads();

    // ---- phase A: per-wave digit counts via ballot match; save (rank,ldr,cnt)/round
    uint64_t creg[WROUNDS];
    uint32_t meta[WROUNDS];
    const uint64_t below = (lane == 0) ? 0ull : (~0ull >> (64 - lane));
    #pragma unroll
    for (int r = 0; r < WROUNDS; ++r) {
        int idx = base + w * WTILE + r * 64 + lane;
        bool active = (idx < N_ROWS);
        uint64_t c = active ? src[idx] : 0ull;
        creg[r] = c;
        uint32_t d = (uint32_t)(c >> SHIFT) & (BINS - 1);
        uint64_t m = __ballot(active ? 1 : 0);
        #pragma unroll
        for (int bb = 0; bb < 8; ++bb) {
            uint64_t x = __ballot((active && ((d >> bb) & 1u)) ? 1 : 0);
            m = ((d >> bb) & 1u) ? (m & x) : (m & ~x);
        }
        int ldr = __ffsll((unsigned long long)m) - 1;
        uint32_t cnt = (uint32_t)__popcll(m);
        uint32_t rank = (uint32_t)__popcll(m & below);
        meta[r] = rank | ((uint32_t)(ldr < 0 ? 0 : ldr) << 8) | (cnt << 16);
        if (active && lane == ldr)
            atomicAdd(&cnt32[w * BINS + d], cnt);
    }
    __syncthreads();   // cnt32 complete

    // ---- phase B1: dual block-exclusive scans over digits (tot -> exT, lc -> exL)
    uint32_t sT = tot, sL = lc;
    #pragma unroll
    for (int off = 1; off < 64; off <<= 1) {
        uint32_t aT = __shfl_up(sT, off, 64);
        uint32_t aL = __shfl_up(sL, off, 64);
        if (lane >= off) { sT += aT; sL += aL; }
    }
    if (lane == 63) { wpT[w] = sT; wpL[w] = sL; }
    __syncthreads();
    uint32_t exT = sT - tot, exL = sL - lc;
    #pragma unroll
    for (int wv = 0; wv < SWAVES; ++wv) if (wv < w) { exT += wpT[wv]; exL += wpL[wv]; }

    // ---- phase B2: writeBase + per-wave cursors (thread t owns digit t)
    if (t < BINS) {
        writeBase[t] = exT + rp - exL;
        uint32_t run = exL;
        #pragma unroll
        for (int wv = 0; wv < SWAVES; ++wv) {
            uint32_t c0 = cnt32[wv * BINS + t];
            cnt32[wv * BINS + t] = run;
            run += c0;
        }
    }
    __syncthreads();

    // ---- phase C: ballot-free — leader atomicAdd on cursor, shfl, LDS scatter
    #pragma unroll
    for (int r = 0; r < WROUNDS; ++r) {
        int idx = base + w * WTILE + r * 64 + lane;
        bool active = (idx < N_ROWS);
        uint64_t c = creg[r];
        uint32_t d = (uint32_t)(c >> SHIFT) & (BINS - 1);
        uint32_t mt = meta[r];
        uint32_t rank = mt & 0xFFu;
        int ldr = (int)((mt >> 8) & 0xFFu);
        uint32_t cnt = mt >> 16;
        uint32_t before = 0;
        if (active && lane == ldr)
            before = atomicAdd(&cnt32[w * BINS + d], cnt);
        before = __shfl(before, ldr, 64);
        if (active) tileS[before + rank] = c;
    }
    __syncthreads();

    // ---- write-out: consecutive sorted positions share digit -> 256B avg segments
    #pragma unroll
    for (int r = 0; r < TILE / STHREADS; ++r) {
        int p = r * STHREADS + t;
        if (p < tileCount) {
            uint64_t c = tileS[p];
            uint32_t d = (uint32_t)(c >> SHIFT) & (BINS - 1);
            uint32_t g = writeBase[d] + p;
            if (!LAST) {
                dst[(size_t)g] = c;
            } else if (g >= LB) {        // only selected range is read; payload only
                dst32[g] = (uint32_t)c;
            }
        }
    }
}

__global__ void finalize(const uint32_t* __restrict__ pay, const float* __restrict__ td,
                         const float* __restrict__ mxtab, float* __restrict__ out) {
    int g = blockIdx.x * 256 + threadIdx.x;
    if (g >= G_CNT) return;
    uint4 p4 = *(const uint4*)(pay + LB + (size_t)g * 4);
    uint32_t cs[4] = {p4.x, p4.y, p4.z, p4.w};
    float maxmin = -100000.0f;
    int maxindex = -100;
    #pragma unroll
    for (int j = 0; j < 4; ++j) {
        int tp = (int)(cs[j] & 0x1FFFFFu);
        bool re1 = ((cs[j] >> 21) & 1u) != 0u;
        float mx = mxtab[tp];
        bool gt = (mx > maxmin);
        if (re1 == gt) { maxmin = mx; maxindex = tp; }
    }
    int mi = maxindex < 0 ? 0 : maxindex;   // clip lower bound; upper never binds
    float4 row = *(const float4*)(td + (size_t)mi * 4);
    *(float4*)(out + (size_t)g * 4) = row;
}

extern "C" void kernel_launch(void* const* d_in, const int* in_sizes, int n_in,
                              void* d_out, int out_size, void* d_ws, size_t ws_size,
                              hipStream_t stream) {
    const float* td = (const float*)d_in[0];
    const float* nb = (const float*)d_in[1];
    float* out = (float*)d_out;
    uint8_t* ws = (uint8_t*)d_ws;

    // layout: mxtab 6MB | gH 256*246*4 ~252KB | A @8MB | B @24MB (~39.3MB used)
    float*    mxtab = (float*)(ws);
    uint32_t* gH    = (uint32_t*)(ws + (size_t)6 * 1024 * 1024);
    uint64_t* A     = (uint64_t*)(ws + (size_t)8 * 1024 * 1024);
    uint64_t* B     = (uint64_t*)(ws + (size_t)24 * 1024 * 1024);

    build_all<<<NBLK + NB_MX, HTHREADS, 0, stream>>>(nb, td, A, mxtab, gH);

    // pass 0: code bits [32,40) — histogram fused into build
    radix_rowscan<<<BINS, 64, 0, stream>>>(gH);
    radix_scatter<32, false><<<NBLK, STHREADS, 0, stream>>>(A, B, nullptr, gH);

    // pass 1: bits [40,48) — uniform digit
    radix_hist_u<8><<<NBLK, HTHREADS, 0, stream>>>(B, gH);
    radix_rowscan<<<BINS, 64, 0, stream>>>(gH);
    radix_scatter<40, false><<<NBLK, STHREADS, 0, stream>>>(B, A, nullptr, gH);

    // pass 2: bits [48,56) — uniform digit
    radix_hist_u<16><<<NBLK, HTHREADS, 0, stream>>>(A, gH);
    radix_rowscan<<<BINS, 64, 0, stream>>>(gH);
    radix_scatter<48, false><<<NBLK, STHREADS, 0, stream>>>(A, B, nullptr, gH);

    // pass 3: bits [56,64) — skewed digit; slim payload-only writes in selected range
    radix_hist_s<24><<<NBLK, HTHREADS, 0, stream>>>(B, gH);
    radix_rowscan<<<BINS, 64, 0, stream>>>(gH);
    radix_scatter<56, true><<<NBLK, STHREADS, 0, stream>>>(B, nullptr, (uint32_t*)A, gH);

    finalize<<<(G_CNT + 255) / 256, 256, 0, stream>>>((const uint32_t*)A, td, mxtab, out);
}